// Round 19
// baseline (91.467 us; speedup 1.0000x reference)
//
#include <hip/hip_runtime.h>
#include <math.h>

constexpr int H_ = 180, W_ = 320, RF_ = 16, K_ = 20, T_ = 400;
constexpr int HW_ = H_ * W_;
constexpr int NWIN = T_ - K_ + 1;   // 381
constexpr int PW   = W_ + 2 * RF_;  // 352 (padded width used by rf_indices)
constexpr float ALPHA = 50.0f, BETA = 1.0f, GAMMA = 0.0f;
constexpr int NROWS = 165;          // possible r0c values 0..164
constexpr int CAP   = 32;           // max tasks per lattice row (~22 actual)
constexpr int NSLICE = 32;          // t-slices: 16x13 + 16x12 frames

// ---------------------------------------------------------------------------
// VALU-pipe cross-lane primitives (proven R10/R13)
// ---------------------------------------------------------------------------
template <int CTRL>
__device__ inline float dpp_add(float v) {
    int s = __builtin_amdgcn_update_dpp(0, __float_as_int(v), CTRL, 0xF, 0xF, true);
    return v + __int_as_float(s);
}
__device__ inline float swz_xor4_add(float v) {
    return v + __int_as_float(
        __builtin_amdgcn_ds_swizzle(__float_as_int(v), 0x101F));  // lane^4
}
#if __has_builtin(__builtin_amdgcn_permlane32_swap)
__device__ inline float pl32_merge(float a, float b) {
    auto r = __builtin_amdgcn_permlane32_swap(
        __float_as_uint(a), __float_as_uint(b), false, false);
    return __uint_as_float(r[0]) + __uint_as_float(r[1]);
}
#else
__device__ inline float pl32_merge(float a, float b) {
    bool hi = (threadIdx.x & 32) != 0;
    float keep = hi ? b : a, send = hi ? a : b;
    return keep + __shfl_xor(send, 32, 64);
}
#endif
#if __has_builtin(__builtin_amdgcn_permlane16_swap)
__device__ inline float pl16_merge(float a, float b) {
    auto r = __builtin_amdgcn_permlane16_swap(
        __float_as_uint(a), __float_as_uint(b), false, false);
    return __uint_as_float(r[0]) + __uint_as_float(r[1]);
}
#else
__device__ inline float pl16_merge(float a, float b) {
    bool hi = (threadIdx.x & 16) != 0;
    float keep = hi ? b : a, send = hi ? a : b;
    return keep + __shfl_xor(send, 16, 64);
}
#endif
__device__ inline float allred64(float v) {
    v = dpp_add<0xB1>(v);    // xor 1
    v = dpp_add<0x4E>(v);    // xor 2
    v = swz_xor4_add(v);     // xor 4
    v = dpp_add<0x128>(v);   // xor 8 (row_ror:8)
    v = pl16_merge(v, v);    // xor 16
    v = pl32_merge(v, v);    // xor 32
    return v;
}
// 8-value multi-reduce: lane 8j ends holding the full wave-sum of acc[j].
__device__ inline float multired8(const float* acc, bool b8) {
    float m0 = pl32_merge(acc[0], acc[4]);
    float m1 = pl32_merge(acc[1], acc[5]);
    float m2 = pl32_merge(acc[2], acc[6]);
    float m3 = pl32_merge(acc[3], acc[7]);
    float n0 = pl16_merge(m0, m2);
    float n1 = pl16_merge(m1, m3);
    float c0v = dpp_add<0x128>(n0);
    float c1v = dpp_add<0x128>(n1);
    float C = b8 ? c1v : c0v;
    C = dpp_add<0xB1>(C);
    C = dpp_add<0x4E>(C);
    C = swz_xor4_add(C);
    return C;
}

// ---------------------------------------------------------------------------
// prep: waves 0-7 factorize w (exact rank-1) -> spatial[256] + temporal[K];
// waves 8-15 build PAIR tasks bucketed by lattice row (key = clamped window
// top r0c): neurons (2i,2i+1) sharing padded row v0 -> one task; else two
// degenerate singles (n,n). Task int4 = { n1|n2<<16, r0c*W+c0c1,
// delta_words, packed(dr+8, dc1+8, dc2+8) } — R13's exact descriptor.
// ---------------------------------------------------------------------------
__global__ __launch_bounds__(1024) void prep_kernel(
    const float* __restrict__ w, const int* __restrict__ rf,
    float* __restrict__ spatial, float* __restrict__ temporal,
    int* __restrict__ cnt, int4* __restrict__ tasks, int N)
{
    __shared__ float ss[32];
    int tid = threadIdx.x, wv = tid >> 6, l = tid & 63;
    if (tid < 256) cnt[tid] = 0;
    __syncthreads();

    if (wv < 8) {
        for (int k = wv; k < K_; k += 8) {
            float s = 0.0f;
#pragma unroll
            for (int j = 0; j < 4; ++j) {
                float v = w[k * 256 + l + j * 64];
                s = fmaf(v, v, s);
            }
            s = allred64(s);
            if (l == 0) ss[k] = s;
        }
    } else {
        auto emit = [&](int n1, int n2, int b1, int b2) {
            int v1  = b1 / PW;
            int r0  = v1 - RF_;
            int c01 = (b1 - v1 * PW) - RF_;
            int r0c = min(max(r0, 0), H_ - RF_);
            int c0c1 = min(max(c01, 0), W_ - RF_);
            int c02  = (b2 - (b2 / PW) * PW) - RF_;
            int c0c2 = min(max(c02, 0), W_ - RF_);
            int slot = atomicAdd(&cnt[r0c], 1);
            int4 d;
            d.x = n1 | (n2 << 16);
            d.y = r0c * W_ + c0c1;
            d.z = c0c2 - c0c1;
            d.w = (r0c - r0 + 8) | ((c0c1 - c01 + 8) << 8)
                                 | ((c0c2 - c02 + 8) << 16);
            tasks[r0c * CAP + slot] = d;
        };
        for (int i = tid - 512; 2 * i < N; i += 512) {
            int n1 = 2 * i, n2 = 2 * i + 1;
            int b1 = rf[n1 * 256];
            if (n2 < N) {
                int b2 = rf[n2 * 256];
                if (b2 / PW == b1 / PW) {
                    emit(n1, n2, b1, b2);
                } else {
                    emit(n1, n1, b1, b1);
                    emit(n2, n2, b2, b2);
                }
            } else {
                emit(n1, n1, b1, b1);
            }
        }
    }
    __syncthreads();

    float best = -1.0f;
    int k0 = 0;
    for (int k = 0; k < K_; ++k) {
        float v = ss[k];
        if (v > best) { best = v; k0 = k; }
    }
    if (wv < 8) {
        for (int k = wv; k < K_; k += 8) {
            float d = 0.0f;
#pragma unroll
            for (int j = 0; j < 4; ++j)
                d = fmaf(w[k * 256 + l + j * 64], w[k0 * 256 + l + j * 64], d);
            d = allred64(d);
            if (l == 0) temporal[k] = d / best;
        }
    }
    if (tid < 256) spatial[tid] = w[k0 * 256 + tid];
}

// ---------------------------------------------------------------------------
// Stage 1 (lattice-row L1 blocking): block = (row bucket, t-slice), 4 waves.
// Per frame: the block's waves cover ALL pair-tasks of one lattice row
// (taskid = wid, wid+4, ...), then __syncthreads() -> the frame's 16-row x
// 320-px band (20 KB < 32 KB L1) is filled into L1 once and reused by every
// task, instead of each pair refetching its own lines. Unique L1 fills drop
// ~6.5M -> ~3.5M lines. Per-task state ~35 VGPR (no arrays -> no spill;
// the R14-18 failure mode). Slice -> XCD pinned via blockIdx low bits.
// Per task-frame: 2 window loads + 2 guarded weight loads + 8 FMA +
// multired8 (acc[8] = {dotA, dotB, 0..}); lane 0 stores n1, lane 8 stores n2.
// ---------------------------------------------------------------------------
__global__ __launch_bounds__(256) void stage1_kernel(
    const float* __restrict__ x, const int* __restrict__ cnt,
    const int4* __restrict__ tasks, const float* __restrict__ spatial,
    float* __restrict__ y)
{
    int bi  = blockIdx.x;
    int slo = bi & 7;
    int shi = (bi >> 3) & 3;
    int row = bi >> 5;
    int s   = (shi << 3) | slo;                     // slice 0..31
    int t0   = (s < 16) ? s * 13 : 208 + (s - 16) * 12;
    int tlen = (s < 16) ? 13 : 12;

    int count = cnt[row];
    if (count == 0) return;                         // block-uniform exit

    int lane = threadIdx.x & 63;
    int wid  = threadIdx.x >> 6;
    int r = lane >> 2;
    int q = lane & 3;
    bool b8 = (lane & 8) != 0;
    const int4* list = tasks + row * CAP;

    for (int f = 0; f < tlen; ++f) {
        int t = t0 + f;
        const float* fp = x + (size_t)t * HW_;
        for (int ti = wid; ti < count; ti += 4) {
            int4 d = list[ti];                      // wave-uniform -> SGPR
            int n1 = d.x & 0xFFFF;
            int n2 = (d.x >> 16) & 0xFFFF;
            int dr  = (d.w & 0xFF) - 8;
            int dc1 = ((d.w >> 8) & 0xFF) - 8;
            int dc2 = ((d.w >> 16) & 0xFF) - 8;

            int rr = r + dr;
            bool rok = (rr >= 0) & (rr < RF_);
            int cc1 = 4 * q + dc1;
            int cc2 = 4 * q + dc2;
            float4 w1 = make_float4(0.f, 0.f, 0.f, 0.f), w2 = w1;
            if (rok & (cc1 >= 0) & (cc1 < RF_))
                w1 = *reinterpret_cast<const float4*>(spatial + rr * RF_ + cc1);
            if (rok & (cc2 >= 0) & (cc2 < RF_))
                w2 = *reinterpret_cast<const float4*>(spatial + rr * RF_ + cc2);

            int off = d.y + r * W_ + 4 * q;
            float4 A = *reinterpret_cast<const float4*>(fp + off);
            float4 B = *reinterpret_cast<const float4*>(fp + off + d.z);

            float u = A.x * w1.x;
            u = fmaf(A.y, w1.y, u);
            u = fmaf(A.z, w1.z, u);
            u = fmaf(A.w, w1.w, u);
            float v = B.x * w2.x;
            v = fmaf(B.y, w2.y, v);
            v = fmaf(B.z, w2.z, v);
            v = fmaf(B.w, w2.w, v);

            float acc[8] = {u, v, 0.f, 0.f, 0.f, 0.f, 0.f, 0.f};
            float C = multired8(acc, b8);
            if (lane == 0)      y[(size_t)n1 * T_ + t] = C;
            else if (lane == 8) y[(size_t)n2 * T_ + t] = C;
        }
        __syncthreads();                            // frame lockstep (L1 reuse)
    }
}

// ---------------------------------------------------------------------------
// Stage 2: out[n, t0] = ALPHA * softplus(BETA * (sum_k y[n,t0+k]*temporal[k]
//                                                 - GAMMA))
// ---------------------------------------------------------------------------
__global__ void stage2_kernel(const float* __restrict__ y,
                              const float* __restrict__ temporal,
                              float* __restrict__ out, int N)
{
    __shared__ float tw[K_];
    if (threadIdx.x < K_) tw[threadIdx.x] = temporal[threadIdx.x];
    __syncthreads();

    int n  = blockIdx.x;
    int t0 = threadIdx.x;
    if (n >= N || t0 >= NWIN) return;

    const float* yn = y + (size_t)n * T_;
    float g = 0.0f;
#pragma unroll
    for (int k = 0; k < K_; ++k)
        g = fmaf(yn[t0 + k], tw[k], g);

    float z = BETA * (g - GAMMA);
    float sp = fmaxf(z, 0.0f) + log1pf(expf(-fabsf(z)));
    out[n * NWIN + t0] = ALPHA * sp;
}

// ---------------------------------------------------------------------------
extern "C" void kernel_launch(void* const* d_in, const int* in_sizes, int n_in,
                              void* d_out, int out_size, void* d_ws, size_t ws_size,
                              hipStream_t stream)
{
    const float* x  = (const float*)d_in[0];  // (T, H, W) f32
    const float* w  = (const float*)d_in[1];  // (K*RF*RF,) f32
    const int*   rf = (const int*)d_in[2];    // (N, 256) i32

    int N = in_sizes[2] / (RF_ * RF_);

    // ws layout (4B words): [0,256) spatial | [256,320) temporal |
    // [320,576) cnt (256 buckets) | [576, 576+4*NROWS*CAP) tasks | y : N*T
    float* spatial  = (float*)d_ws;
    float* temporal = spatial + 256;
    int*   cnt      = (int*)d_ws + 320;
    int4*  tasks    = (int4*)((int*)d_ws + 576);
    float* y        = (float*)d_ws + 576 + 4 * NROWS * CAP;

    prep_kernel<<<1, 1024, 0, stream>>>(w, rf, spatial, temporal, cnt, tasks, N);
    stage1_kernel<<<NROWS * NSLICE, 256, 0, stream>>>(x, cnt, tasks, spatial, y);
    stage2_kernel<<<N, 384, 0, stream>>>(y, temporal, (float*)d_out, N);
}

// Round 20
// 41.025 us; speedup vs baseline: 2.2295x; 2.2295x over previous
//
#include <hip/hip_runtime.h>
#include <math.h>

constexpr int H_ = 180, W_ = 320, RF_ = 16, K_ = 20, T_ = 400;
constexpr int HW_ = H_ * W_;
constexpr int NWIN = T_ - K_ + 1;   // 381
constexpr int PW   = W_ + 2 * RF_;  // 352 (padded width used by rf_indices)
constexpr float ALPHA = 50.0f, BETA = 1.0f, GAMMA = 0.0f;
constexpr int NXCD = 8;
constexpr int T_PER_XCD = T_ / NXCD;     // 50 frames per XCD
constexpr int T_HALF = T_PER_XCD / 2;    // 25 frames per wave
constexpr int CH = 8;                    // frames per reduction chunk

// ---------------------------------------------------------------------------
// VALU-pipe cross-lane primitives (proven R10/R13)
// ---------------------------------------------------------------------------
template <int CTRL>
__device__ inline float dpp_add(float v) {
    int s = __builtin_amdgcn_update_dpp(0, __float_as_int(v), CTRL, 0xF, 0xF, true);
    return v + __int_as_float(s);
}
__device__ inline float swz_xor4_add(float v) {
    return v + __int_as_float(
        __builtin_amdgcn_ds_swizzle(__float_as_int(v), 0x101F));  // lane^4
}
#if __has_builtin(__builtin_amdgcn_permlane32_swap)
__device__ inline float pl32_merge(float a, float b) {
    auto r = __builtin_amdgcn_permlane32_swap(
        __float_as_uint(a), __float_as_uint(b), false, false);
    return __uint_as_float(r[0]) + __uint_as_float(r[1]);
}
#else
__device__ inline float pl32_merge(float a, float b) {
    bool hi = (threadIdx.x & 32) != 0;
    float keep = hi ? b : a, send = hi ? a : b;
    return keep + __shfl_xor(send, 32, 64);
}
#endif
#if __has_builtin(__builtin_amdgcn_permlane16_swap)
__device__ inline float pl16_merge(float a, float b) {
    auto r = __builtin_amdgcn_permlane16_swap(
        __float_as_uint(a), __float_as_uint(b), false, false);
    return __uint_as_float(r[0]) + __uint_as_float(r[1]);
}
#else
__device__ inline float pl16_merge(float a, float b) {
    bool hi = (threadIdx.x & 16) != 0;
    float keep = hi ? b : a, send = hi ? a : b;
    return keep + __shfl_xor(send, 16, 64);
}
#endif
__device__ inline float allred64(float v) {
    v = dpp_add<0xB1>(v);    // xor 1
    v = dpp_add<0x4E>(v);    // xor 2
    v = swz_xor4_add(v);     // xor 4
    v = dpp_add<0x128>(v);   // xor 8 (row_ror:8)
    v = pl16_merge(v, v);    // xor 16
    v = pl32_merge(v, v);    // xor 32
    return v;
}

// 8-value multi-reduce over the wave (proven R10): input acc[0..7] per lane,
// output: lane 8j holds the full wave-sum of logical acc[j].
__device__ inline float multired8(const float* acc, bool b8) {
    float m0 = pl32_merge(acc[0], acc[4]);
    float m1 = pl32_merge(acc[1], acc[5]);
    float m2 = pl32_merge(acc[2], acc[6]);
    float m3 = pl32_merge(acc[3], acc[7]);
    float n0 = pl16_merge(m0, m2);
    float n1 = pl16_merge(m1, m3);
    float c0v = dpp_add<0x128>(n0);
    float c1v = dpp_add<0x128>(n1);
    float C = b8 ? c1v : c0v;
    C = dpp_add<0xB1>(C);
    C = dpp_add<0x4E>(C);
    C = swz_xor4_add(C);
    return C;
}

// ---------------------------------------------------------------------------
// prep: (a) factorize w (exact rank-1) -> spatial[256] + temporal[K] (waves
// 0-7); (b) build PAIR TASKS (waves 8-15): neurons (2i, 2i+1) sharing the
// same padded row (=> same y, same row clamp) become one task; otherwise
// degenerate single tasks (n,n). Descriptor: {n1|n2<<16, A word base,
// delta words, packed (dr, dc1, dc2) weight shifts}.
// ---------------------------------------------------------------------------
__global__ __launch_bounds__(1024) void prep_kernel(
    const float* __restrict__ w, const int* __restrict__ rf,
    float* __restrict__ spatial, float* __restrict__ temporal,
    int* __restrict__ cnt, int4* __restrict__ tasks, int N)
{
    __shared__ float ss[32];
    int tid = threadIdx.x, wv = tid >> 6, l = tid & 63;
    if (tid == 0) *cnt = 0;
    __syncthreads();

    if (wv < 8) {
        for (int k = wv; k < K_; k += 8) {
            float s = 0.0f;
#pragma unroll
            for (int j = 0; j < 4; ++j) {
                float v = w[k * 256 + l + j * 64];
                s = fmaf(v, v, s);
            }
            s = allred64(s);
            if (l == 0) ss[k] = s;
        }
    } else {
        for (int i = tid - 512; 2 * i < N; i += 512) {
            int n1 = 2 * i, n2 = 2 * i + 1;
            int b1 = rf[n1 * 256];
            int v1 = b1 / PW;
            int pn2 = n1, b2 = b1, v2 = v1;
            bool paired = false;
            if (n2 < N) {
                b2 = rf[n2 * 256];
                v2 = b2 / PW;
                paired = (v2 == v1);
            }
            // emit task for (n1, paired ? n2 : n1)
            {
                int r0  = v1 - RF_;
                int c01 = (b1 - v1 * PW) - RF_;
                int r0c = min(max(r0, 0), H_ - RF_);
                int c0c1 = min(max(c01, 0), W_ - RF_);
                int c02  = paired ? ((b2 - v2 * PW) - RF_) : c01;
                int c0c2 = min(max(c02, 0), W_ - RF_);
                pn2 = paired ? n2 : n1;
                int4 d;
                d.x = n1 | (pn2 << 16);
                d.y = r0c * W_ + c0c1;
                d.z = c0c2 - c0c1;
                d.w = (r0c - r0 + 8) | ((c0c1 - c01 + 8) << 8)
                                     | ((c0c2 - c02 + 8) << 16);
                tasks[atomicAdd(cnt, 1)] = d;
            }
            if (!paired && n2 < N) {   // n2 as its own single task
                int r0  = v2 - RF_;
                int c02 = (b2 - v2 * PW) - RF_;
                int r0c = min(max(r0, 0), H_ - RF_);
                int c0c2 = min(max(c02, 0), W_ - RF_);
                int4 d;
                d.x = n2 | (n2 << 16);
                d.y = r0c * W_ + c0c2;
                d.z = 0;
                d.w = (r0c - r0 + 8) | ((c0c2 - c02 + 8) << 8)
                                     | ((c0c2 - c02 + 8) << 16);
                tasks[atomicAdd(cnt, 1)] = d;
            }
        }
    }
    __syncthreads();

    float best = -1.0f;
    int k0 = 0;
    for (int k = 0; k < K_; ++k) {
        float v = ss[k];
        if (v > best) { best = v; k0 = k; }
    }
    if (wv < 8) {
        for (int k = wv; k < K_; k += 8) {
            float d = 0.0f;
#pragma unroll
            for (int j = 0; j < 4; ++j)
                d = fmaf(w[k * 256 + l + j * 64], w[k0 * 256 + l + j * 64], d);
            d = allred64(d);
            if (l == 0) temporal[k] = d / best;
        }
    }
    if (tid < 256) spatial[tid] = w[k0 * 256 + tid];
}

// ---------------------------------------------------------------------------
// Stage 1 (pair-gather): one wave = one neuron PAIR x 25 frames.
// Lane (r = lane>>2, s = lane&3) loads chunk s of window1 (A) and chunk s of
// window2 (B = A + delta*4B, delta <= 8 px) -> the pair's union rows touch
// ~2.25 lines instead of 3.5 (1.53x fewer L1 line-fills); request count per
// neuron unchanged. Same weight float4 feeds both accumulators (shifted-
// weight trick handles clamped borders; dc is always a multiple of 4 on the
// mosaic lattice). 8-frame chunks; two multired8 per chunk; lane 8j stores
// frame j. Degenerate tasks (n,n) reuse the identical path.
// ---------------------------------------------------------------------------
__global__ __launch_bounds__(256) void stage1_kernel(
    const float* __restrict__ x, const int4* __restrict__ tasks,
    const int* __restrict__ cnt, const float* __restrict__ spatial,
    float* __restrict__ y)
{
    int lane = threadIdx.x & 63;
    int wid  = threadIdx.x >> 6;

    int b    = blockIdx.x;
    int xcd  = b & (NXCD - 1);
    int rest = b >> 3;
    int half = rest & 1;
    int tg   = rest >> 1;

    int taskid = tg * 4 + wid;
    if (taskid >= *cnt) return;

    int4 d = tasks[taskid];
    int n1 = d.x & 0xFFFF;
    int n2 = d.x >> 16;
    int delta = d.z;
    int dr  = (d.w & 0xFF) - 8;
    int dc1 = ((d.w >> 8) & 0xFF) - 8;
    int dc2 = ((d.w >> 16) & 0xFF) - 8;

    int t0 = xcd * T_PER_XCD + half * T_HALF;

    int r = lane >> 2;
    int s = lane & 3;

    // weights (float4 from spatial or zero; dc multiple of 4)
    int rr = r + dr;
    bool rok = (rr >= 0) & (rr < RF_);
    int cc1 = 4 * s + dc1;
    int cc2 = 4 * s + dc2;
    float4 w1 = make_float4(0.f, 0.f, 0.f, 0.f), w2 = w1;
    if (rok & (cc1 >= 0) & (cc1 < RF_))
        w1 = *reinterpret_cast<const float4*>(spatial + rr * RF_ + cc1);
    if (rok & (cc2 >= 0) & (cc2 < RF_))
        w2 = *reinterpret_cast<const float4*>(spatial + rr * RF_ + cc2);

    int offA = d.y + r * W_ + 4 * s;
    const float* xp = x + (size_t)t0 * HW_;
    float* yp1 = y + (size_t)n1 * T_ + t0;
    float* yp2 = y + (size_t)n2 * T_ + t0;

    bool b8 = (lane & 8) != 0;

    // 3 full chunks of 8 frames (local 0..23)
    for (int tt = 0; tt < 24; tt += CH) {
        float4 A[CH], B[CH];
#pragma unroll
        for (int j = 0; j < CH; ++j) {
            const float* fp = xp + (size_t)(tt + j) * HW_ + offA;
            A[j] = *reinterpret_cast<const float4*>(fp);
            B[j] = *reinterpret_cast<const float4*>(fp + delta);
        }
        float a1[CH], a2[CH];
#pragma unroll
        for (int j = 0; j < CH; ++j) {
            float u = A[j].x * w1.x;
            u = fmaf(A[j].y, w1.y, u);
            u = fmaf(A[j].z, w1.z, u);
            a1[j] = fmaf(A[j].w, w1.w, u);
            float v = B[j].x * w2.x;
            v = fmaf(B[j].y, w2.y, v);
            v = fmaf(B[j].z, w2.z, v);
            a2[j] = fmaf(B[j].w, w2.w, v);
        }
        float C1 = multired8(a1, b8);
        float C2 = multired8(a2, b8);
        if ((lane & 7) == 0) {
            yp1[tt + (lane >> 3)] = C1;
            yp2[tt + (lane >> 3)] = C2;
        }
    }

    // tail frame (local 24)
    {
        const float* fp = xp + (size_t)24 * HW_ + offA;
        float4 A = *reinterpret_cast<const float4*>(fp);
        float4 B = *reinterpret_cast<const float4*>(fp + delta);
        float u = A.x * w1.x;
        u = fmaf(A.y, w1.y, u);
        u = fmaf(A.z, w1.z, u);
        u = fmaf(A.w, w1.w, u);
        float v = B.x * w2.x;
        v = fmaf(B.y, w2.y, v);
        v = fmaf(B.z, w2.z, v);
        v = fmaf(B.w, w2.w, v);
        u = allred64(u);
        v = allred64(v);
        if (lane == 0) {
            yp1[24] = u;
            yp2[24] = v;
        }
    }
}

// ---------------------------------------------------------------------------
// Stage 2: out[n, t0] = ALPHA * softplus(BETA * (sum_k y[n,t0+k]*temporal[k]
//                                                 - GAMMA))
// ---------------------------------------------------------------------------
__global__ void stage2_kernel(const float* __restrict__ y,
                              const float* __restrict__ temporal,
                              float* __restrict__ out, int N)
{
    __shared__ float tw[K_];
    if (threadIdx.x < K_) tw[threadIdx.x] = temporal[threadIdx.x];
    __syncthreads();

    int n  = blockIdx.x;
    int t0 = threadIdx.x;
    if (n >= N || t0 >= NWIN) return;

    const float* yn = y + (size_t)n * T_;
    float g = 0.0f;
#pragma unroll
    for (int k = 0; k < K_; ++k)
        g = fmaf(yn[t0 + k], tw[k], g);

    float z = BETA * (g - GAMMA);
    float sp = fmaxf(z, 0.0f) + log1pf(expf(-fabsf(z)));
    out[n * NWIN + t0] = ALPHA * sp;
}

// ---------------------------------------------------------------------------
extern "C" void kernel_launch(void* const* d_in, const int* in_sizes, int n_in,
                              void* d_out, int out_size, void* d_ws, size_t ws_size,
                              hipStream_t stream)
{
    const float* x  = (const float*)d_in[0];  // (T, H, W) f32
    const float* w  = (const float*)d_in[1];  // (K*RF*RF,) f32
    const int*   rf = (const int*)d_in[2];    // (N, 256) i32

    int N = in_sizes[2] / (RF_ * RF_);

    // ws layout (4B words): [0,256) spatial | [256,320) temporal |
    // [320,384) cnt | [384, 384+4N) tasks (int4) | y : N*T
    float* spatial  = (float*)d_ws;
    float* temporal = spatial + 256;
    int*   cnt      = (int*)d_ws + 320;
    int4*  tasks    = (int4*)((int*)d_ws + 384);
    float* y        = (float*)d_ws + 384 + 4 * N;

    // grid sized for worst case (all singles = N tasks); excess waves exit.
    int NTG = (N + 3) / 4;
    prep_kernel<<<1, 1024, 0, stream>>>(w, rf, spatial, temporal, cnt, tasks, N);
    stage1_kernel<<<NXCD * NTG * 2, 256, 0, stream>>>(x, tasks, cnt, spatial, y);
    stage2_kernel<<<N, 384, 0, stream>>>(y, temporal, (float*)d_out, N);
}